// Round 5
// baseline (845.349 us; speedup 1.0000x reference)
//
#include <hip/hip_runtime.h>
#include <hip/hip_bf16.h>

#define G1 __attribute__((address_space(1)))
#define L3 __attribute__((address_space(3)))

typedef __bf16 bf16x8 __attribute__((ext_vector_type(8)));
typedef _Float16 half4 __attribute__((ext_vector_type(4)));
typedef float f32x4 __attribute__((ext_vector_type(4)));

#if __has_builtin(__builtin_amdgcn_exp2f)
#define EXP2F(x) __builtin_amdgcn_exp2f(x)
#else
#define EXP2F(x) __expf((x) * 0.69314718056f)
#endif

__device__ __forceinline__ ushort f2bf(float f) {
  union { float f; uint u; } v; v.f = f;
  uint u = v.u;
  u += 0x7fffu + ((u >> 16) & 1u);   // RNE
  return (ushort)(u >> 16);
}
__device__ __forceinline__ ushort f2h(float f) {
  _Float16 h = (_Float16)f;
  union { _Float16 h; ushort u; } v; v.h = h;
  return v.u;
}

// ---------------- cast fp32 -> bf16 ----------------
__global__ void cast_bf16_kernel(const float* __restrict__ in, ushort* __restrict__ out, int n4) {
  int i = blockIdx.x * 256 + threadIdx.x;
  if (i >= n4) return;
  float4 v = ((const float4*)in)[i];
  ushort4 o;
  o.x = f2bf(v.x); o.y = f2bf(v.y); o.z = f2bf(v.z); o.w = f2bf(v.w);
  ((ushort4*)out)[i] = o;
}

// mask2 = mask * log2(e)  (exp2-domain softmax)
__global__ void scale_mask_kernel(const float* __restrict__ in, float* __restrict__ out, int n) {
  int i = blockIdx.x * 256 + threadIdx.x;
  if (i < n) out[i] = in[i] * 1.44269504088896f;
}

// ---------------- 256x256 bt-GEMM, BK=32 ring-of-4, 1 phase/tile ----------------
// out[m][n] = sum_k A[m][k]*B[n][k] + bias[n]
// MODE 2: plain, fp32 out row-major [m][2048]  (proj)
// MODE 3: fused QKV: seg = n0/2048 picks {B,bias,out}; seg<2 -> bf16 (bh,t,d);
//         seg==2 -> fp16 transposed (bh,d,t)
// 512 threads (2x4 waves), per-wave 128x64 out. LDS 128KB: ring-4 of (A,B) 16KB tiles.
// Per tile: 12 ds_read_b128 + 4 global_load_lds + barrier + lgkm(0) + 32 MFMA +
// vmcnt(8) + barrier.  Invariant after tile t's drain: outstanding = loads of
// tiles {t+2, t+3} (8) and tile t+1 fully landed.
#define STAGE_A(bf, kt) {                                                       \
    __builtin_amdgcn_global_load_lds((G1 uint*)(Ag0 + (kt) * 32),               \
        (L3 uint*)&As[bf][tid * 8], 16, 0, 0);                                  \
    __builtin_amdgcn_global_load_lds((G1 uint*)(Ag1 + (kt) * 32),               \
        (L3 uint*)&As[bf][4096 + tid * 8], 16, 0, 0);                           \
  }
#define STAGE_B(bf, kt) {                                                       \
    __builtin_amdgcn_global_load_lds((G1 uint*)(Bg0 + (kt) * 32),               \
        (L3 uint*)&Bs[bf][tid * 8], 16, 0, 0);                                  \
    __builtin_amdgcn_global_load_lds((G1 uint*)(Bg1 + (kt) * 32),               \
        (L3 uint*)&Bs[bf][4096 + tid * 8], 16, 0, 0);                           \
  }

template <int MODE>
__global__ __launch_bounds__(512, 2)
void gemm256(const ushort* __restrict__ A,
             const ushort* __restrict__ B0, const ushort* __restrict__ B1,
             const ushort* __restrict__ B2,
             const float* __restrict__ bias0, const float* __restrict__ bias1,
             const float* __restrict__ bias2,
             void* __restrict__ out0, void* __restrict__ out1, void* __restrict__ out2,
             int nbn, int K) {
  __shared__ ushort As[4][8192];   // [buf][256 rows x 32 k] = 16KB each
  __shared__ ushort Bs[4][8192];
  const int tid  = threadIdx.x;
  const int wave = tid >> 6, lane = tid & 63;
  const int l15  = lane & 15, quad = lane >> 4;

  // bijective XCD swizzle (nwg divisible by 8), m-major tile order
  const int nwg = gridDim.x;
  const int cpx = nwg >> 3;
  const int swz = (blockIdx.x & 7) * cpx + (blockIdx.x >> 3);
  const int m0 = (swz / nbn) * 256;
  const int n0g = (swz % nbn) * 256;

  int seg = 0, nn = n0g;
  const ushort* Bmat = B0;
  const float* bias = bias0;
  if (MODE == 3) {
    seg = n0g >> 11;
    nn  = n0g & 2047;
    Bmat = seg == 0 ? B0 : (seg == 1 ? B1 : B2);
    bias = seg == 0 ? bias0 : (seg == 1 ? bias1 : bias2);
  }

  const int wm = (wave >> 2) << 7;    // 0 or 128
  const int wn = (wave & 3) << 6;     // 0,64,128,192

  // frag read: row*32 + (quad ^ ((row>>1)&3))*8, row = base16+l15 -> bank-uniform
  const int fck = (quad ^ ((l15 >> 1) & 3)) << 3;

  // stage addressing (same involution on the source side; LDS dest linear)
  const int srow = tid >> 2;
  const int sck  = ((tid & 3) ^ ((srow >> 1) & 3)) * 8;
  const ushort* Ag0 = A    + (size_t)(m0 + srow) * K + sck;
  const ushort* Ag1 = A    + (size_t)(m0 + 128 + srow) * K + sck;
  const ushort* Bg0 = Bmat + (size_t)(nn + srow) * K + sck;
  const ushort* Bg1 = Bmat + (size_t)(nn + 128 + srow) * K + sck;

  f32x4 acc[8][4] = {};

  // prologue: stage tiles 0,1,2 (12 loads); vmcnt(8) -> tile 0 landed
  STAGE_A(0, 0) STAGE_B(0, 0)
  STAGE_A(1, 1) STAGE_B(1, 1)
  STAGE_A(2, 2) STAGE_B(2, 2)
  asm volatile("s_waitcnt vmcnt(8)" ::: "memory");
  __builtin_amdgcn_s_barrier();

  const int NT = K >> 5;               // 64 K-tiles
  for (int j = 0; j < NT; j += 4) {
#pragma unroll
    for (int tt = 0; tt < 4; ++tt) {
      const int t   = j + tt;
      const int kt3 = (t + 3) & (NT - 1);   // wrap: staged but never read
      const int b3  = (tt + 3) & 3;
      bf16x8 bfr[4], af[8];
#pragma unroll
      for (int ni = 0; ni < 4; ++ni)
        bfr[ni] = *(const bf16x8*)&Bs[tt][(wn + ni * 16 + l15) * 32 + fck];
#pragma unroll
      for (int mi = 0; mi < 8; ++mi)
        af[mi] = *(const bf16x8*)&As[tt][(wm + mi * 16 + l15) * 32 + fck];
      STAGE_A(b3, kt3) STAGE_B(b3, kt3)
      __builtin_amdgcn_s_barrier();
      asm volatile("s_waitcnt lgkmcnt(0)" ::: "memory");
      __builtin_amdgcn_s_setprio(1);
#pragma unroll
      for (int mi = 0; mi < 8; ++mi)
#pragma unroll
        for (int ni = 0; ni < 4; ++ni)
          acc[mi][ni] = __builtin_amdgcn_mfma_f32_16x16x32_bf16(af[mi], bfr[ni], acc[mi][ni], 0, 0, 0);
      __builtin_amdgcn_s_setprio(0);
      asm volatile("s_waitcnt vmcnt(8)" ::: "memory");
      __builtin_amdgcn_s_barrier();
    }
  }
  asm volatile("s_waitcnt vmcnt(0)" ::: "memory");   // DMA must not outlive block

  // epilogue: m = m0+wm+mi*16+quad*4+r, n = nn+wn+ni*16+l15 (C/D row=quad*4+r, col=l15)
  if (MODE == 3 && seg == 2) {
#pragma unroll
    for (int mi = 0; mi < 8; ++mi)
#pragma unroll
      for (int ni = 0; ni < 4; ++ni) {
        int n = nn + wn + ni * 16 + l15;
        float bv = bias[n];
        int mbase = m0 + wm + mi * 16 + quad * 4;
        int b = mbase >> 11, tq = mbase & 2047, h = n >> 7, dd = n & 127;
        ushort4 o;
        o.x = f2h(acc[mi][ni][0] + bv);
        o.y = f2h(acc[mi][ni][1] + bv);
        o.z = f2h(acc[mi][ni][2] + bv);
        o.w = f2h(acc[mi][ni][3] + bv);
        *(ushort4*)&((ushort*)out2)[(((size_t)(b * 16 + h) * 128 + dd) << 11) + tq] = o;
      }
  } else if (MODE == 3) {
    ushort* dst = seg == 0 ? (ushort*)out0 : (ushort*)out1;
#pragma unroll
    for (int mi = 0; mi < 8; ++mi)
#pragma unroll
      for (int ni = 0; ni < 4; ++ni) {
        int n = nn + wn + ni * 16 + l15;
        float bv = bias[n];
        int mbase = m0 + wm + mi * 16 + quad * 4;
#pragma unroll
        for (int r = 0; r < 4; ++r) {
          int m = mbase + r;
          int b = m >> 11, tq = m & 2047, h = n >> 7, dd = n & 127;
          dst[(((size_t)(b * 16 + h) * 2048 + tq) << 7) + dd] = f2bf(acc[mi][ni][r] + bv);
        }
      }
  } else {
#pragma unroll
    for (int mi = 0; mi < 8; ++mi)
#pragma unroll
      for (int ni = 0; ni < 4; ++ni) {
        int n = n0g + wn + ni * 16 + l15;
        float bv = bias[n];
        int mbase = m0 + wm + mi * 16 + quad * 4;
#pragma unroll
        for (int r = 0; r < 4; ++r)
          ((float*)out0)[(size_t)(mbase + r) * 2048 + n] = acc[mi][ni][r] + bv;
      }
  }
}

// ---------------- flash attention (S^T form), 8 waves, dbuf K/V ----------------
// Q,K: (bh,t,d) bf16.  Vt: (bh,d,t) fp16.  Y: (b,t,C) bf16.  mask2 = mask*log2e.
// 512 threads = 8 waves x 32 q-rows (block covers 256 q-rows); KVBLK=64 dbuf.
// exp2-domain softmax; defer-max (THR=10 in log2 domain); causal cndmask only on
// the wave's single diagonal tile.
__global__ __launch_bounds__(512, 4)
void attn_kernel(const ushort* __restrict__ Q, const ushort* __restrict__ Kh,
                 const ushort* __restrict__ Vt, const float* __restrict__ mask2,
                 ushort* __restrict__ Y) {
  __shared__ ushort Ks[2][8192];   // 64 t x 128 d, chunk(t,ck) at t*16 + (ck^(t&15))
  __shared__ ushort Vs[2][8192];   // 128 d x 64 t, chunk(d,ck) at d*8  + (ck^(d&7))
  const int tid  = threadIdx.x;
  const int wave = tid >> 6, lane = tid & 63;
  const int l15  = lane & 15, quad = lane >> 4;
  const int bh = blockIdx.x;
  const int qb = 7 - blockIdx.y;              // longest blocks dispatch first
  const int b  = bh >> 4, h = bh & 15;
  const int qw0 = qb * 256 + wave * 32;
  const ushort* Qb = Q  + (size_t)bh * 2048 * 128;
  const ushort* Kb = Kh + (size_t)bh * 2048 * 128;
  const ushort* Vb = Vt + (size_t)bh * 128 * 2048;
  const float*  mrow = mask2 + b * 2048;

  // Q B-frags (persistent): lane l15 = qr, k=d = dk*32+quad*8..+7
  bf16x8 aq[2][4];
#pragma unroll
  for (int q2 = 0; q2 < 2; ++q2)
#pragma unroll
    for (int dk = 0; dk < 4; ++dk)
      aq[q2][dk] = *(const bf16x8*)(Qb + (size_t)(qw0 + q2 * 16 + l15) * 128 + dk * 32 + quad * 8);

  auto stageKV = [&](int itn, int bufb) {
    const int k0s = itn * 64;
#pragma unroll
    for (int i = 0; i < 2; ++i) {
      int c = i * 512 + tid;                      // K chunk 0..1023
      int t = c >> 4, ckG = (c & 15) ^ (t & 15);
      __builtin_amdgcn_global_load_lds((G1 uint*)(Kb + (size_t)(k0s + t) * 128 + ckG * 8),
                                       (L3 uint*)&Ks[bufb][c * 8], 16, 0, 0);
    }
#pragma unroll
    for (int i = 0; i < 2; ++i) {
      int c = i * 512 + tid;                      // V chunk 0..1023
      int d = c >> 3, ckG = (c & 7) ^ (d & 7);
      __builtin_amdgcn_global_load_lds((G1 uint*)(Vb + (size_t)d * 2048 + k0s + ckG * 8),
                                       (L3 uint*)&Vs[bufb][c * 8], 16, 0, 0);
    }
  };

  float mi_[2], li[2];
  f32x4 OT[8][2] = {};   // OT[ddt][q2]: rows dd=ddt*16+quad*4+r, cols qr=q2*16+l15
  mi_[0] = mi_[1] = -3.0e38f;
  li[0] = li[1] = 0.f;

  const float scale2 = 0.08838834764831845f * 1.44269504088896f;  // /sqrt(128) * log2e
  const int nkt = 4 * qb + 4;

  stageKV(0, 0);   // prologue
  for (int it = 0; it < nkt; ++it) {
    const int k0 = it * 64;
    const int bb = it & 1;
    asm volatile("s_waitcnt vmcnt(0)" ::: "memory");   // tile it landed (this wave)
    __builtin_amdgcn_s_barrier();                      // ... for all waves
    if (it + 1 < nkt) stageKV(it + 1, bb ^ 1);         // in flight across compute

    if (k0 <= qw0 + 31) {    // tile intersects this wave's causal range
      // S^T: A = K (lane l15 = kc-row), B = Q
      f32x4 s[2][4] = {};
#pragma unroll
      for (int ns = 0; ns < 4; ++ns) {
        bf16x8 kb[4];
#pragma unroll
        for (int dk = 0; dk < 4; ++dk) {
          int ck = ((dk * 4 + quad) ^ l15);   // swizzled chunk
          kb[dk] = *(const bf16x8*)&Ks[bb][(ns * 16 + l15) * 128 + ck * 8];
        }
#pragma unroll
        for (int q2 = 0; q2 < 2; ++q2)
#pragma unroll
          for (int dk = 0; dk < 4; ++dk)
            s[q2][ns] = __builtin_amdgcn_mfma_f32_16x16x32_bf16(kb[dk], aq[q2][dk], s[q2][ns], 0, 0, 0);
      }

      const bool dmask = (k0 + 63 > qw0);   // wave-uniform: single diagonal tile
      half4 pf[2][4];
#pragma unroll
      for (int q2 = 0; q2 < 2; ++q2) {
        const int qr = qw0 + q2 * 16 + l15;
        float4 mk[4];
#pragma unroll
        for (int ns = 0; ns < 4; ++ns)
          mk[ns] = *(const float4*)&mrow[k0 + ns * 16 + quad * 4];
        // v2 = s*scale2 + mask2  (exp2 domain)
#pragma unroll
        for (int ns = 0; ns < 4; ++ns)
#pragma unroll
          for (int r = 0; r < 4; ++r)
            s[q2][ns][r] = fmaf(s[q2][ns][r], scale2, mk[ns][r]);
        if (dmask) {
#pragma unroll
          for (int ns = 0; ns < 4; ++ns)
#pragma unroll
            for (int r = 0; r < 4; ++r) {
              int kc = k0 + ns * 16 + quad * 4 + r;
              if (kc > qr) s[q2][ns][r] = -3.0e38f;
            }
        }
        // row max (state replicated across quads)
        float rm = -3.0e38f;
#pragma unroll
        for (int ns = 0; ns < 4; ++ns)
          rm = fmaxf(rm, fmaxf(fmaxf(s[q2][ns][0], s[q2][ns][1]), fmaxf(s[q2][ns][2], s[q2][ns][3])));
        rm = fmaxf(rm, __shfl_xor(rm, 16));
        rm = fmaxf(rm, __shfl_xor(rm, 32));
        // defer-max: skip rescale while tile max stays within 2^10 of running max
        const bool skip = __all(rm <= mi_[q2] + 10.0f);
        float mnew = mi_[q2], al = 1.0f;
        if (!skip) {
          mnew = fmaxf(mi_[q2], rm);
          al = EXP2F(mi_[q2] - mnew);
        }
        float rs = 0.f;
#pragma unroll
        for (int ns = 0; ns < 4; ++ns) {
#pragma unroll
          for (int r = 0; r < 4; ++r) {
            float p = EXP2F(s[q2][ns][r] - mnew);
            s[q2][ns][r] = p;
            rs += p;
          }
#if __has_builtin(__builtin_amdgcn_cvt_pkrtz)
          {
            auto lo = __builtin_amdgcn_cvt_pkrtz(s[q2][ns][0], s[q2][ns][1]);
            auto hi = __builtin_amdgcn_cvt_pkrtz(s[q2][ns][2], s[q2][ns][3]);
            pf[q2][ns] = half4{(_Float16)lo[0], (_Float16)lo[1],
                               (_Float16)hi[0], (_Float16)hi[1]};
          }
#else
          pf[q2][ns] = half4{(_Float16)s[q2][ns][0], (_Float16)s[q2][ns][1],
                             (_Float16)s[q2][ns][2], (_Float16)s[q2][ns][3]};
#endif
        }
        rs += __shfl_xor(rs, 16);
        rs += __shfl_xor(rs, 32);
        if (skip) {
          li[q2] += rs;
        } else {
          li[q2] = li[q2] * al + rs;
          mi_[q2] = mnew;
#pragma unroll
          for (int ddt = 0; ddt < 8; ++ddt) OT[ddt][q2] *= al;
        }
      }

      // PV: OT[ddt][q2] += mfma_16x16x16_f16(A=V^T frag, B=P frag)
#pragma unroll
      for (int ns = 0; ns < 4; ++ns)
#pragma unroll
        for (int ddt = 0; ddt < 8; ++ddt) {
          int row = ddt * 16 + l15;
          int ck = (2 * ns + (quad >> 1)) ^ (l15 & 7);   // swizzled 16B chunk
          half4 vf = *(const half4*)&Vs[bb][row * 64 + ck * 8 + (quad & 1) * 4];
#pragma unroll
          for (int q2 = 0; q2 < 2; ++q2)
            OT[ddt][q2] = __builtin_amdgcn_mfma_f32_16x16x16f16(vf, pf[q2][ns], OT[ddt][q2], 0, 0, 0);
        }
    }
    __builtin_amdgcn_s_barrier();   // all reads of buf bb done before next stage to it
  }

  // epilogue: O[qr][dd] = OT[dd][qr] / li
#pragma unroll
  for (int q2 = 0; q2 < 2; ++q2) {
    float inv = 1.0f / li[q2];
    int t = qw0 + q2 * 16 + l15;
#pragma unroll
    for (int ddt = 0; ddt < 8; ++ddt) {
      ushort4 o;
      o.x = f2bf(OT[ddt][q2][0] * inv);
      o.y = f2bf(OT[ddt][q2][1] * inv);
      o.z = f2bf(OT[ddt][q2][2] * inv);
      o.w = f2bf(OT[ddt][q2][3] * inv);
      *(ushort4*)&Y[((size_t)(b * 2048 + t)) * 2048 + h * 128 + ddt * 16 + quad * 4] = o;
    }
  }
}

extern "C" void kernel_launch(void* const* d_in, const int* in_sizes, int n_in,
                              void* d_out, int out_size, void* d_ws, size_t ws_size,
                              hipStream_t stream) {
  const float* x     = (const float*)d_in[0];
  const float* amask = (const float*)d_in[1];
  const float* Wq = (const float*)d_in[2];
  const float* bq = (const float*)d_in[3];
  const float* Wk = (const float*)d_in[4];
  const float* bk = (const float*)d_in[5];
  const float* Wv = (const float*)d_in[6];
  const float* bv = (const float*)d_in[7];
  const float* Wp = (const float*)d_in[8];
  const float* bp = (const float*)d_in[9];

  char* ws = (char*)d_ws;
  ushort* xb  = (ushort*)(ws);                  // 8192x2048 bf16 = 32MB
  ushort* Wqb = (ushort*)(ws + 33554432);       // 8MB each
  ushort* Wkb = (ushort*)(ws + 41943040);
  ushort* Wvb = (ushort*)(ws + 50331648);
  ushort* Wpb = (ushort*)(ws + 58720256);
  ushort* Qb  = (ushort*)(ws + 67108864);       // (bh,t,d) bf16 32MB
  ushort* Kb  = (ushort*)(ws + 100663296);      // (bh,t,d) bf16 32MB
  ushort* Vtb = (ushort*)(ws + 134217728);      // (bh,d,t) fp16 32MB
  ushort* Yb  = (ushort*)(ws + 167772160);      // (b*t, C) bf16 32MB
  float* mask2 = (float*)d_out;                 // scratch; proj gemm overwrites all

  cast_bf16_kernel<<<16384, 256, 0, stream>>>(x,  xb,  4194304);
  cast_bf16_kernel<<<4096,  256, 0, stream>>>(Wq, Wqb, 1048576);
  cast_bf16_kernel<<<4096,  256, 0, stream>>>(Wk, Wkb, 1048576);
  cast_bf16_kernel<<<4096,  256, 0, stream>>>(Wv, Wvb, 1048576);
  cast_bf16_kernel<<<4096,  256, 0, stream>>>(Wp, Wpb, 1048576);
  scale_mask_kernel<<<32, 256, 0, stream>>>(amask, mask2, 8192);

  // fused QKV: (8192/256) x (6144/256) = 32 x 24 = 768 blocks
  gemm256<3><<<768, 512, 0, stream>>>(xb, Wqb, Wkb, Wvb, bq, bk, bv,
                                      Qb, Kb, Vtb, 24, 2048);

  attn_kernel<<<dim3(64, 8), 512, 0, stream>>>(Qb, Kb, Vtb, mask2, Yb);

  // proj: 32 x 8 = 256 blocks
  gemm256<2><<<256, 512, 0, stream>>>(Yb, Wpb, nullptr, nullptr, bp, nullptr, nullptr,
                                      d_out, nullptr, nullptr, 8, 2048);
}

// Round 6
// 565.887 us; speedup vs baseline: 1.4938x; 1.4938x over previous
//
#include <hip/hip_runtime.h>
#include <hip/hip_bf16.h>

#define G1 __attribute__((address_space(1)))
#define L3 __attribute__((address_space(3)))

typedef __bf16 bf16x8 __attribute__((ext_vector_type(8)));
typedef _Float16 half4 __attribute__((ext_vector_type(4)));
typedef float f32x4 __attribute__((ext_vector_type(4)));

#if __has_builtin(__builtin_amdgcn_exp2f)
#define EXP2F(x) __builtin_amdgcn_exp2f(x)
#else
#define EXP2F(x) __expf((x) * 0.69314718056f)
#endif

__device__ __forceinline__ ushort f2bf(float f) {
  union { float f; uint u; } v; v.f = f;
  uint u = v.u;
  u += 0x7fffu + ((u >> 16) & 1u);   // RNE
  return (ushort)(u >> 16);
}
__device__ __forceinline__ ushort f2h(float f) {
  _Float16 h = (_Float16)f;
  union { _Float16 h; ushort u; } v; v.h = h;
  return v.u;
}

// ---------------- cast fp32 -> bf16 ----------------
__global__ void cast_bf16_kernel(const float* __restrict__ in, ushort* __restrict__ out, int n4) {
  int i = blockIdx.x * 256 + threadIdx.x;
  if (i >= n4) return;
  float4 v = ((const float4*)in)[i];
  ushort4 o;
  o.x = f2bf(v.x); o.y = f2bf(v.y); o.z = f2bf(v.z); o.w = f2bf(v.w);
  ((ushort4*)out)[i] = o;
}

// mask2 = mask * log2(e)  (exp2-domain softmax)
__global__ void scale_mask_kernel(const float* __restrict__ in, float* __restrict__ out, int n) {
  int i = blockIdx.x * 256 + threadIdx.x;
  if (i < n) out[i] = in[i] * 1.44269504088896f;
}

// ---------------- 256x256 bt-GEMM, BK=32 ring-of-4, 1 phase/tile ----------------
// out[m][n] = sum_k A[m][k]*B[n][k] + bias[n]
// MODE 2: plain, fp32 out row-major [m][2048]  (proj)
// MODE 3: fused QKV: seg = n0/2048 picks {B,bias,out}; seg<2 -> bf16 (bh,t,d);
//         seg==2 -> fp16 transposed (bh,d,t)
#define STAGE_A(bf, kt) {                                                       \
    __builtin_amdgcn_global_load_lds((G1 uint*)(Ag0 + (kt) * 32),               \
        (L3 uint*)&As[bf][tid * 8], 16, 0, 0);                                  \
    __builtin_amdgcn_global_load_lds((G1 uint*)(Ag1 + (kt) * 32),               \
        (L3 uint*)&As[bf][4096 + tid * 8], 16, 0, 0);                           \
  }
#define STAGE_B(bf, kt) {                                                       \
    __builtin_amdgcn_global_load_lds((G1 uint*)(Bg0 + (kt) * 32),               \
        (L3 uint*)&Bs[bf][tid * 8], 16, 0, 0);                                  \
    __builtin_amdgcn_global_load_lds((G1 uint*)(Bg1 + (kt) * 32),               \
        (L3 uint*)&Bs[bf][4096 + tid * 8], 16, 0, 0);                           \
  }

template <int MODE>
__global__ __launch_bounds__(512, 2)
void gemm256(const ushort* __restrict__ A,
             const ushort* __restrict__ B0, const ushort* __restrict__ B1,
             const ushort* __restrict__ B2,
             const float* __restrict__ bias0, const float* __restrict__ bias1,
             const float* __restrict__ bias2,
             void* __restrict__ out0, void* __restrict__ out1, void* __restrict__ out2,
             int nbn, int K) {
  __shared__ ushort As[4][8192];   // [buf][256 rows x 32 k] = 16KB each
  __shared__ ushort Bs[4][8192];
  const int tid  = threadIdx.x;
  const int wave = tid >> 6, lane = tid & 63;
  const int l15  = lane & 15, quad = lane >> 4;

  // bijective XCD swizzle (nwg divisible by 8), m-major tile order
  const int nwg = gridDim.x;
  const int cpx = nwg >> 3;
  const int swz = (blockIdx.x & 7) * cpx + (blockIdx.x >> 3);
  const int m0 = (swz / nbn) * 256;
  const int n0g = (swz % nbn) * 256;

  int seg = 0, nn = n0g;
  const ushort* Bmat = B0;
  const float* bias = bias0;
  if (MODE == 3) {
    seg = n0g >> 11;
    nn  = n0g & 2047;
    Bmat = seg == 0 ? B0 : (seg == 1 ? B1 : B2);
    bias = seg == 0 ? bias0 : (seg == 1 ? bias1 : bias2);
  }

  const int wm = (wave >> 2) << 7;    // 0 or 128
  const int wn = (wave & 3) << 6;     // 0,64,128,192

  // frag read: row*32 + (quad ^ ((row>>1)&3))*8, row = base16+l15 -> bank-uniform
  const int fck = (quad ^ ((l15 >> 1) & 3)) << 3;

  // stage addressing (same involution on the source side; LDS dest linear)
  const int srow = tid >> 2;
  const int sck  = ((tid & 3) ^ ((srow >> 1) & 3)) * 8;
  const ushort* Ag0 = A    + (size_t)(m0 + srow) * K + sck;
  const ushort* Ag1 = A    + (size_t)(m0 + 128 + srow) * K + sck;
  const ushort* Bg0 = Bmat + (size_t)(nn + srow) * K + sck;
  const ushort* Bg1 = Bmat + (size_t)(nn + 128 + srow) * K + sck;

  f32x4 acc[8][4] = {};

  // prologue: stage tiles 0,1,2 (12 loads); vmcnt(8) -> tile 0 landed
  STAGE_A(0, 0) STAGE_B(0, 0)
  STAGE_A(1, 1) STAGE_B(1, 1)
  STAGE_A(2, 2) STAGE_B(2, 2)
  asm volatile("s_waitcnt vmcnt(8)" ::: "memory");
  __builtin_amdgcn_s_barrier();

  const int NT = K >> 5;               // 64 K-tiles
  for (int j = 0; j < NT; j += 4) {
#pragma unroll
    for (int tt = 0; tt < 4; ++tt) {
      const int t   = j + tt;
      const int kt3 = (t + 3) & (NT - 1);   // wrap: staged but never read
      const int b3  = (tt + 3) & 3;
      bf16x8 bfr[4], af[8];
#pragma unroll
      for (int ni = 0; ni < 4; ++ni)
        bfr[ni] = *(const bf16x8*)&Bs[tt][(wn + ni * 16 + l15) * 32 + fck];
#pragma unroll
      for (int mi = 0; mi < 8; ++mi)
        af[mi] = *(const bf16x8*)&As[tt][(wm + mi * 16 + l15) * 32 + fck];
      STAGE_A(b3, kt3) STAGE_B(b3, kt3)
      __builtin_amdgcn_s_barrier();
      asm volatile("s_waitcnt lgkmcnt(0)" ::: "memory");
      __builtin_amdgcn_s_setprio(1);
#pragma unroll
      for (int mi = 0; mi < 8; ++mi)
#pragma unroll
        for (int ni = 0; ni < 4; ++ni)
          acc[mi][ni] = __builtin_amdgcn_mfma_f32_16x16x32_bf16(af[mi], bfr[ni], acc[mi][ni], 0, 0, 0);
      __builtin_amdgcn_s_setprio(0);
      asm volatile("s_waitcnt vmcnt(8)" ::: "memory");
      __builtin_amdgcn_s_barrier();
    }
  }
  asm volatile("s_waitcnt vmcnt(0)" ::: "memory");   // DMA must not outlive block

  // epilogue: m = m0+wm+mi*16+quad*4+r, n = nn+wn+ni*16+l15 (C/D row=quad*4+r, col=l15)
  if (MODE == 3 && seg == 2) {
#pragma unroll
    for (int mi = 0; mi < 8; ++mi)
#pragma unroll
      for (int ni = 0; ni < 4; ++ni) {
        int n = nn + wn + ni * 16 + l15;
        float bv = bias[n];
        int mbase = m0 + wm + mi * 16 + quad * 4;
        int b = mbase >> 11, tq = mbase & 2047, h = n >> 7, dd = n & 127;
        ushort4 o;
        o.x = f2h(acc[mi][ni][0] + bv);
        o.y = f2h(acc[mi][ni][1] + bv);
        o.z = f2h(acc[mi][ni][2] + bv);
        o.w = f2h(acc[mi][ni][3] + bv);
        *(ushort4*)&((ushort*)out2)[(((size_t)(b * 16 + h) * 128 + dd) << 11) + tq] = o;
      }
  } else if (MODE == 3) {
    ushort* dst = seg == 0 ? (ushort*)out0 : (ushort*)out1;
#pragma unroll
    for (int mi = 0; mi < 8; ++mi)
#pragma unroll
      for (int ni = 0; ni < 4; ++ni) {
        int n = nn + wn + ni * 16 + l15;
        float bv = bias[n];
        int mbase = m0 + wm + mi * 16 + quad * 4;
#pragma unroll
        for (int r = 0; r < 4; ++r) {
          int m = mbase + r;
          int b = m >> 11, tq = m & 2047, h = n >> 7, dd = n & 127;
          dst[(((size_t)(b * 16 + h) * 2048 + tq) << 7) + dd] = f2bf(acc[mi][ni][r] + bv);
        }
      }
  } else {
#pragma unroll
    for (int mi = 0; mi < 8; ++mi)
#pragma unroll
      for (int ni = 0; ni < 4; ++ni) {
        int n = n0g + wn + ni * 16 + l15;
        float bv = bias[n];
        int mbase = m0 + wm + mi * 16 + quad * 4;
#pragma unroll
        for (int r = 0; r < 4; ++r)
          ((float*)out0)[(size_t)(mbase + r) * 2048 + n] = acc[mi][ni][r] + bv;
      }
  }
}

// ---------------- flash attention (S^T form), 4 waves, dbuf K/V, VALU diet ------
// Q,K: (bh,t,d) bf16.  Vt: (bh,d,t) fp16.  Y: (b,t,C) bf16.  mask2 = mask*log2e.
// 256 threads = 4 waves x 32 q-rows (block = 128 q-rows); KVBLK=64 dbuf.
// exp2-domain softmax; defer-max (THR=10 in log2 domain); causal cndmask only on
// diagonal tiles (wave-uniform).  launch_bounds(256,2): VGPR cap 256, no spill.
__global__ __launch_bounds__(256, 2)
void attn_kernel(const ushort* __restrict__ Q, const ushort* __restrict__ Kh,
                 const ushort* __restrict__ Vt, const float* __restrict__ mask2,
                 ushort* __restrict__ Y) {
  __shared__ ushort Ks[2][8192];   // 64 t x 128 d, chunk(t,ck) at t*16 + (ck^(t&15))
  __shared__ ushort Vs[2][8192];   // 128 d x 64 t, chunk(d,ck) at d*8  + (ck^(d&7))
  const int tid  = threadIdx.x;
  const int wave = tid >> 6, lane = tid & 63;
  const int l15  = lane & 15, quad = lane >> 4;
  const int bh = blockIdx.x;                  // bh-major
  const int qt = 15 - blockIdx.y;             // longest blocks dispatch first
  const int b  = bh >> 4, h = bh & 15;
  const int qw0 = qt * 128 + wave * 32;
  const ushort* Qb = Q  + (size_t)bh * 2048 * 128;
  const ushort* Kb = Kh + (size_t)bh * 2048 * 128;
  const ushort* Vb = Vt + (size_t)bh * 128 * 2048;
  const float*  mrow = mask2 + b * 2048;

  // Q B-frags (persistent): lane l15 = qr, k=d = dk*32+quad*8..+7
  bf16x8 aq[2][4];
#pragma unroll
  for (int q2 = 0; q2 < 2; ++q2)
#pragma unroll
    for (int dk = 0; dk < 4; ++dk)
      aq[q2][dk] = *(const bf16x8*)(Qb + (size_t)(qw0 + q2 * 16 + l15) * 128 + dk * 32 + quad * 8);

  auto stageKV = [&](int itn, int bufb) {
    const int k0s = itn * 64;
#pragma unroll
    for (int i = 0; i < 4; ++i) {
      int c = i * 256 + tid;                      // K chunk 0..1023
      int t = c >> 4, ckG = (c & 15) ^ (t & 15);
      __builtin_amdgcn_global_load_lds((G1 uint*)(Kb + (size_t)(k0s + t) * 128 + ckG * 8),
                                       (L3 uint*)&Ks[bufb][c * 8], 16, 0, 0);
    }
#pragma unroll
    for (int i = 0; i < 4; ++i) {
      int c = i * 256 + tid;                      // V chunk 0..1023
      int d = c >> 3, ckG = (c & 7) ^ (d & 7);
      __builtin_amdgcn_global_load_lds((G1 uint*)(Vb + (size_t)d * 2048 + k0s + ckG * 8),
                                       (L3 uint*)&Vs[bufb][c * 8], 16, 0, 0);
    }
  };

  float mi_[2], li[2];
  f32x4 OT[8][2] = {};   // OT[ddt][q2]: rows dd=ddt*16+quad*4+r, cols qr=q2*16+l15
  mi_[0] = mi_[1] = -3.0e38f;
  li[0] = li[1] = 0.f;

  const float scale2 = 0.08838834764831845f * 1.44269504088896f;  // /sqrt(128) * log2e
  const int nkt = 2 * qt + 2;

  stageKV(0, 0);   // prologue
  for (int it = 0; it < nkt; ++it) {
    const int k0 = it * 64;
    const int bb = it & 1;
    asm volatile("s_waitcnt vmcnt(0)" ::: "memory");   // tile it landed (this wave)
    __builtin_amdgcn_s_barrier();                      // ... for all waves
    if (it + 1 < nkt) stageKV(it + 1, bb ^ 1);         // in flight across compute

    if (k0 <= qw0 + 31) {    // tile intersects this wave's causal range
      // S^T: A = K (lane l15 = kc-row), B = Q
      f32x4 s[2][4] = {};
#pragma unroll
      for (int ns = 0; ns < 4; ++ns) {
        bf16x8 kb[4];
#pragma unroll
        for (int dk = 0; dk < 4; ++dk) {
          int ck = ((dk * 4 + quad) ^ l15);   // swizzled chunk
          kb[dk] = *(const bf16x8*)&Ks[bb][(ns * 16 + l15) * 128 + ck * 8];
        }
#pragma unroll
        for (int q2 = 0; q2 < 2; ++q2)
#pragma unroll
          for (int dk = 0; dk < 4; ++dk)
            s[q2][ns] = __builtin_amdgcn_mfma_f32_16x16x32_bf16(kb[dk], aq[q2][dk], s[q2][ns], 0, 0, 0);
      }

      // mask loaded once per tile (same for both q2)
      float4 mk[4];
#pragma unroll
      for (int ns = 0; ns < 4; ++ns)
        mk[ns] = *(const float4*)&mrow[k0 + ns * 16 + quad * 4];

      const bool dmask = (k0 + 63 > qw0);   // wave-uniform: diagonal tiles only
      half4 pf[2][4];
#pragma unroll
      for (int q2 = 0; q2 < 2; ++q2) {
        const int qr = qw0 + q2 * 16 + l15;
        // v2 = s*scale2 + mask2  (exp2 domain)
#pragma unroll
        for (int ns = 0; ns < 4; ++ns)
#pragma unroll
          for (int r = 0; r < 4; ++r)
            s[q2][ns][r] = fmaf(s[q2][ns][r], scale2, mk[ns][r]);
        if (dmask) {
#pragma unroll
          for (int ns = 0; ns < 4; ++ns)
#pragma unroll
            for (int r = 0; r < 4; ++r) {
              int kc = k0 + ns * 16 + quad * 4 + r;
              if (kc > qr) s[q2][ns][r] = -3.0e38f;
            }
        }
        // row max (state replicated across quads)
        float rm = -3.0e38f;
#pragma unroll
        for (int ns = 0; ns < 4; ++ns)
          rm = fmaxf(rm, fmaxf(fmaxf(s[q2][ns][0], s[q2][ns][1]), fmaxf(s[q2][ns][2], s[q2][ns][3])));
        rm = fmaxf(rm, __shfl_xor(rm, 16));
        rm = fmaxf(rm, __shfl_xor(rm, 32));
        // defer-max: skip rescale while tile max stays within 2^10 of running max
        const bool skip = __all(rm <= mi_[q2] + 10.0f);
        float mnew = mi_[q2], al = 1.0f;
        if (!skip) {
          mnew = fmaxf(mi_[q2], rm);
          al = EXP2F(mi_[q2] - mnew);
        }
        float rs = 0.f;
#pragma unroll
        for (int ns = 0; ns < 4; ++ns) {
#pragma unroll
          for (int r = 0; r < 4; ++r) {
            float p = EXP2F(s[q2][ns][r] - mnew);
            s[q2][ns][r] = p;
            rs += p;
          }
#if __has_builtin(__builtin_amdgcn_cvt_pkrtz)
          {
            auto lo = __builtin_amdgcn_cvt_pkrtz(s[q2][ns][0], s[q2][ns][1]);
            auto hi = __builtin_amdgcn_cvt_pkrtz(s[q2][ns][2], s[q2][ns][3]);
            pf[q2][ns] = half4{(_Float16)lo[0], (_Float16)lo[1],
                               (_Float16)hi[0], (_Float16)hi[1]};
          }
#else
          pf[q2][ns] = half4{(_Float16)s[q2][ns][0], (_Float16)s[q2][ns][1],
                             (_Float16)s[q2][ns][2], (_Float16)s[q2][ns][3]};
#endif
        }
        rs += __shfl_xor(rs, 16);
        rs += __shfl_xor(rs, 32);
        if (skip) {
          li[q2] += rs;
        } else {
          li[q2] = li[q2] * al + rs;
          mi_[q2] = mnew;
#pragma unroll
          for (int ddt = 0; ddt < 8; ++ddt) OT[ddt][q2] *= al;
        }
      }

      // PV: OT[ddt][q2] += mfma_16x16x16_f16(A=V^T frag, B=P frag)
#pragma unroll
      for (int ns = 0; ns < 4; ++ns)
#pragma unroll
        for (int ddt = 0; ddt < 8; ++ddt) {
          int row = ddt * 16 + l15;
          int ck = (2 * ns + (quad >> 1)) ^ (l15 & 7);   // swizzled 16B chunk
          half4 vf = *(const half4*)&Vs[bb][row * 64 + ck * 8 + (quad & 1) * 4];
#pragma unroll
          for (int q2 = 0; q2 < 2; ++q2)
            OT[ddt][q2] = __builtin_amdgcn_mfma_f32_16x16x16f16(vf, pf[q2][ns], OT[ddt][q2], 0, 0, 0);
        }
    }
    __builtin_amdgcn_s_barrier();   // all reads of buf bb done before next stage to it
  }

  // epilogue: O[qr][dd] = OT[dd][qr] / li
#pragma unroll
  for (int q2 = 0; q2 < 2; ++q2) {
    float inv = 1.0f / li[q2];
    int t = qw0 + q2 * 16 + l15;
#pragma unroll
    for (int ddt = 0; ddt < 8; ++ddt) {
      ushort4 o;
      o.x = f2bf(OT[ddt][q2][0] * inv);
      o.y = f2bf(OT[ddt][q2][1] * inv);
      o.z = f2bf(OT[ddt][q2][2] * inv);
      o.w = f2bf(OT[ddt][q2][3] * inv);
      *(ushort4*)&Y[((size_t)(b * 2048 + t)) * 2048 + h * 128 + ddt * 16 + quad * 4] = o;
    }
  }
}

extern "C" void kernel_launch(void* const* d_in, const int* in_sizes, int n_in,
                              void* d_out, int out_size, void* d_ws, size_t ws_size,
                              hipStream_t stream) {
  const float* x     = (const float*)d_in[0];
  const float* amask = (const float*)d_in[1];
  const float* Wq = (const float*)d_in[2];
  const float* bq = (const float*)d_in[3];
  const float* Wk = (const float*)d_in[4];
  const float* bk = (const float*)d_in[5];
  const float* Wv = (const float*)d_in[6];
  const float* bv = (const float*)d_in[7];
  const float* Wp = (const float*)d_in[8];
  const float* bp = (const float*)d_in[9];

  char* ws = (char*)d_ws;
  ushort* xb  = (ushort*)(ws);                  // 8192x2048 bf16 = 32MB
  ushort* Wqb = (ushort*)(ws + 33554432);       // 8MB each
  ushort* Wkb = (ushort*)(ws + 41943040);
  ushort* Wvb = (ushort*)(ws + 50331648);
  ushort* Wpb = (ushort*)(ws + 58720256);
  ushort* Qb  = (ushort*)(ws + 67108864);       // (bh,t,d) bf16 32MB
  ushort* Kb  = (ushort*)(ws + 100663296);      // (bh,t,d) bf16 32MB
  ushort* Vtb = (ushort*)(ws + 134217728);      // (bh,d,t) fp16 32MB
  ushort* Yb  = (ushort*)(ws + 167772160);      // (b*t, C) bf16 32MB
  float* mask2 = (float*)d_out;                 // scratch; proj gemm overwrites all

  cast_bf16_kernel<<<16384, 256, 0, stream>>>(x,  xb,  4194304);
  cast_bf16_kernel<<<4096,  256, 0, stream>>>(Wq, Wqb, 1048576);
  cast_bf16_kernel<<<4096,  256, 0, stream>>>(Wk, Wkb, 1048576);
  cast_bf16_kernel<<<4096,  256, 0, stream>>>(Wv, Wvb, 1048576);
  cast_bf16_kernel<<<4096,  256, 0, stream>>>(Wp, Wpb, 1048576);
  scale_mask_kernel<<<32, 256, 0, stream>>>(amask, mask2, 8192);

  // fused QKV: (8192/256) x (6144/256) = 32 x 24 = 768 blocks
  gemm256<3><<<768, 512, 0, stream>>>(xb, Wqb, Wkb, Wvb, bq, bk, bv,
                                      Qb, Kb, Vtb, 24, 2048);

  attn_kernel<<<dim3(64, 16), 256, 0, stream>>>(Qb, Kb, Vtb, mask2, Yb);

  // proj: 32 x 8 = 256 blocks
  gemm256<2><<<256, 512, 0, stream>>>(Yb, Wpb, nullptr, nullptr, bp, nullptr, nullptr,
                                      d_out, nullptr, nullptr, 8, 2048);
}